// Round 6
// baseline (167.539 us; speedup 1.0000x reference)
//
#include <hip/hip_runtime.h>
#include <cmath>

#define B_ 16384
#define S_ 512
#define P_ 1024
#define K_ 8
#define D_ 64
#define H_ 128
#define BT 8       // batch rows per tile; bf16-packed tile = 512*4*4B = 8 KB
#define PADU 4     // u32 per LDS row (4 u32 = 8 bf16 batch values), 16B-aligned for b128
#define GRID_C 512           // blocks for out_kernel; each handles NT/GRID_C = 4 tiles
#define NT (B_ / BT)         // 2048 b-tiles

typedef float f32x2 __attribute__((ext_vector_type(2)));  // clang vector: OK for nontemporal builtins

// float -> bf16 (RNE, finite inputs) packed helpers
static __device__ __forceinline__ unsigned int rne16(float f) {
  unsigned int u = __float_as_uint(f);
  return (u + 0x7fffu + ((u >> 16) & 1u)) >> 16;
}
static __device__ __forceinline__ float bflo(unsigned int u) { return __uint_as_float(u << 16); }
static __device__ __forceinline__ float bfhi(unsigned int u) { return __uint_as_float(u & 0xffff0000u); }

// ---------------- Kernel A: sklproj[s][h] = dot(skl_emd[s,:], U[h,:]) ----------------
__global__ __launch_bounds__(128) void proj_skl_kernel(
    const float* __restrict__ skl_emd, const float* __restrict__ U,
    float* __restrict__ sklproj) {
  __shared__ float row[D_];
  const int s = blockIdx.x, h = threadIdx.x;
  if (h < D_) row[h] = skl_emd[s * D_ + h];
  __syncthreads();
  const float4* __restrict__ Urow = (const float4*)(U + (size_t)h * D_);
  float acc = 0.f;
#pragma unroll
  for (int i = 0; i < D_ / 4; i++) {
    const float4 u = Urow[i];
    acc += row[4 * i] * u.x;
    acc += row[4 * i + 1] * u.y;
    acc += row[4 * i + 2] * u.z;
    acc += row[4 * i + 3] * u.w;
  }
  sklproj[s * H_ + h] = acc;
}

// ---------------- Kernel B: att[p][k] = softmax_k( sum_h v[h]*tanh(projP[p][h]+sklproj[g[p][k]][h]) )
__global__ __launch_bounds__(128) void att_kernel(
    const float* __restrict__ plm_emd, const float* __restrict__ W,
    const float* __restrict__ vT, const float* __restrict__ sklproj,
    const int* __restrict__ gidx, float* __restrict__ att) {
  __shared__ float prow[D_];
  __shared__ float red[2][K_];
  const int p = blockIdx.x, h = threadIdx.x;
  if (h < D_) prow[h] = plm_emd[p * D_ + h];
  __syncthreads();
  const float4* __restrict__ Wrow = (const float4*)(W + (size_t)h * D_);
  float pp = 0.f;
#pragma unroll
  for (int i = 0; i < D_ / 4; i++) {
    const float4 w = Wrow[i];
    pp += prow[4 * i] * w.x;
    pp += prow[4 * i + 1] * w.y;
    pp += prow[4 * i + 2] * w.z;
    pp += prow[4 * i + 3] * w.w;
  }
  const float v = vT[h];
  int g[K_];
#pragma unroll
  for (int k = 0; k < K_; k++) g[k] = gidx[p * K_ + k];
  float partial[K_];
#pragma unroll
  for (int k = 0; k < K_; k++) partial[k] = v * tanhf(pp + sklproj[g[k] * H_ + h]);
#pragma unroll
  for (int off = 32; off >= 1; off >>= 1)
#pragma unroll
    for (int k = 0; k < K_; k++) partial[k] += __shfl_down(partial[k], off, 64);
  const int wave = h >> 6, lane = h & 63;
  if (lane == 0)
#pragma unroll
    for (int k = 0; k < K_; k++) red[wave][k] = partial[k];
  __syncthreads();
  if (h == 0) {
    float s[K_], m = -1e30f;
#pragma unroll
    for (int k = 0; k < K_; k++) { s[k] = red[0][k] + red[1][k]; m = fmaxf(m, s[k]); }
    float denom = 0.f;
#pragma unroll
    for (int k = 0; k < K_; k++) { s[k] = expf(s[k] - m); denom += s[k]; }
    const float inv = 1.f / denom;
#pragma unroll
    for (int k = 0; k < K_; k++) att[p * K_ + k] = s[k] * inv;
  }
}

// ---------------- Kernel C: out[b][p] = mask[b][p] * sum_k skl_pfc[b][g[p][k]] * att[p][k]
// R6: write-late (T14). __syncthreads = s_waitcnt vmcnt(0)+s_barrier, and R5
// issued 8 NT stores right before the next barrier -> every tile-phase stalled
// the full store-retire latency with nothing in flight. Now: stores for tile
// n-1 are issued right AFTER barrier(n), draining under GATHER(n). Single
// acc/m2 reg set (STORE(prev) completes before GATHER(cur) refills).
// Pipeline per tile: PACK -> bar -> STORE(prev) -> PREFETCH(next) ->
// LOADMASK(cur) -> GATHER(cur).
__global__ __launch_bounds__(512) void out_kernel(
    const float* __restrict__ skl_pfc, const float* __restrict__ mask,
    const float* __restrict__ att, const int* __restrict__ gidx,
    float* __restrict__ out) {
  __shared__ __align__(16) unsigned int rowsT[2][S_][PADU];  // 16384 B
  const int t = threadIdx.x;      // 0..511
  const int p2 = 2 * t;           // this thread's p pair: p2, p2+1

  // ---- register-cache att + gidx for this thread's 2 p's (tile-invariant) ----
  float aA[K_], aB[K_];
  int gA[K_], gB[K_];
  {
    const float4* ap = (const float4*)(att + (size_t)p2 * K_);
    const int4* gp = (const int4*)(gidx + (size_t)p2 * K_);
    const float4 a0 = ap[0], a1 = ap[1], a2 = ap[2], a3 = ap[3];
    const int4 g0 = gp[0], g1 = gp[1], g2 = gp[2], g3 = gp[3];
    aA[0]=a0.x; aA[1]=a0.y; aA[2]=a0.z; aA[3]=a0.w; aA[4]=a1.x; aA[5]=a1.y; aA[6]=a1.z; aA[7]=a1.w;
    aB[0]=a2.x; aB[1]=a2.y; aB[2]=a2.z; aB[3]=a2.w; aB[4]=a3.x; aB[5]=a3.y; aB[6]=a3.z; aB[7]=a3.w;
    gA[0]=g0.x; gA[1]=g0.y; gA[2]=g0.z; gA[3]=g0.w; gA[4]=g1.x; gA[5]=g1.y; gA[6]=g1.z; gA[7]=g1.w;
    gB[0]=g2.x; gB[1]=g2.y; gB[2]=g2.z; gB[3]=g2.w; gB[4]=g3.x; gB[5]=g3.y; gB[6]=g3.z; gB[7]=g3.w;
  }

  float st[BT];     // prefetch staging for LDS row s = t
  f32x2 m2[BT];     // mask for current tile (consumed by STORE of same tile)
  float acc0[BT], acc1[BT];

  auto PREFETCH = [&](int tile) {
    const int b0 = tile * BT;
#pragma unroll
    for (int b = 0; b < BT; b++)
      st[b] = __builtin_nontemporal_load(&skl_pfc[(size_t)(b0 + b) * S_ + t]);
  };

  auto PACK = [&](int buf) {
    unsigned int pk[PADU];
#pragma unroll
    for (int q = 0; q < PADU; q++)
      pk[q] = rne16(st[2 * q]) | (rne16(st[2 * q + 1]) << 16);
    *(uint4*)&rowsT[buf][t][0] = make_uint4(pk[0], pk[1], pk[2], pk[3]);
  };

  auto LOADMASK = [&](int tile) {
    const int b0 = tile * BT;
#pragma unroll
    for (int bb = 0; bb < BT; bb++)
      m2[bb] = __builtin_nontemporal_load(
          (const f32x2*)&mask[(size_t)(b0 + bb) * P_ + p2]);
  };

  auto GATHER = [&](int buf) {
#pragma unroll
    for (int bb = 0; bb < BT; bb++) { acc0[bb] = 0.f; acc1[bb] = 0.f; }
#pragma unroll
    for (int k = 0; k < K_; k++) {
      const uint4 q0 = *(const uint4*)&rowsT[buf][gA[k]][0];  // bb 0..7 packed bf16
      const float a = aA[k];
      acc0[0] += bflo(q0.x) * a; acc0[1] += bfhi(q0.x) * a;
      acc0[2] += bflo(q0.y) * a; acc0[3] += bfhi(q0.y) * a;
      acc0[4] += bflo(q0.z) * a; acc0[5] += bfhi(q0.z) * a;
      acc0[6] += bflo(q0.w) * a; acc0[7] += bfhi(q0.w) * a;
    }
#pragma unroll
    for (int k = 0; k < K_; k++) {
      const uint4 q1 = *(const uint4*)&rowsT[buf][gB[k]][0];
      const float a = aB[k];
      acc1[0] += bflo(q1.x) * a; acc1[1] += bfhi(q1.x) * a;
      acc1[2] += bflo(q1.y) * a; acc1[3] += bfhi(q1.y) * a;
      acc1[4] += bflo(q1.z) * a; acc1[5] += bfhi(q1.z) * a;
      acc1[6] += bflo(q1.w) * a; acc1[7] += bfhi(q1.w) * a;
    }
  };

  auto STORE = [&](int tile) {
    const int b0 = tile * BT;
#pragma unroll
    for (int bb = 0; bb < BT; bb++) {
      f32x2 o;
      o.x = acc0[bb] * m2[bb].x;
      o.y = acc1[bb] * m2[bb].y;
      __builtin_nontemporal_store(o, (f32x2*)&out[(size_t)(b0 + bb) * P_ + p2]);
    }
  };

  // ---- software pipeline over 4 tiles, write-late ----
  int tile = blockIdx.x;
  int buf = 0;
  PREFETCH(tile);
  PACK(buf);
  __syncthreads();
  {
    const int next = tile + GRID_C;
    if (next < NT) PREFETCH(next);
  }
  LOADMASK(tile);
  GATHER(buf);
  int prev = tile;

  for (int next = tile + GRID_C; next < NT; next += GRID_C) {
    tile = next;
    buf ^= 1;
    PACK(buf);          // waits on prefetch regs (vmcnt auto)
    __syncthreads();    // stores(prev-1) drained long ago; tile buffer ready
    STORE(prev);        // issue prev tile's stores NOW -> drain under GATHER
    const int nn = tile + GRID_C;
    if (nn < NT) PREFETCH(nn);
    LOADMASK(tile);
    GATHER(buf);
    prev = tile;
  }
  STORE(prev);
}

extern "C" void kernel_launch(void* const* d_in, const int* in_sizes, int n_in,
                              void* d_out, int out_size, void* d_ws, size_t ws_size,
                              hipStream_t stream) {
  const float* skl_pfc = (const float*)d_in[0];   // [B, S]
  const float* mask    = (const float*)d_in[1];   // [B, P]
  const float* skl_emd = (const float*)d_in[2];   // [S, D]
  const float* plm_emd = (const float*)d_in[3];   // [P, D]
  const float* W       = (const float*)d_in[4];   // [H, D]
  const float* U       = (const float*)d_in[5];   // [H, D]
  const float* vT      = (const float*)d_in[6];   // [1, H]
  const int*   gidx    = (const int*)d_in[7];     // [P, K]
  float* out = (float*)d_out;                     // [B, P]

  float* sklproj = (float*)d_ws;                  // S*H floats = 256 KB
  float* att     = sklproj + S_ * H_;             // P*K floats = 32 KB

  proj_skl_kernel<<<S_, 128, 0, stream>>>(skl_emd, U, sklproj);
  att_kernel<<<P_, 128, 0, stream>>>(plm_emd, W, vT, sklproj, gidx, att);
  out_kernel<<<GRID_C, 512, 0, stream>>>(skl_pfc, mask, att, gidx, out);
}